// Round 4
// baseline (124.995 us; speedup 1.0000x reference)
//
#include <hip/hip_runtime.h>
#include <cfloat>

// Emu3 VQ-VAE vector quantizer argmin (exact-rounding match to numpy ref):
//   x [9216,4] f32 (channels-last gather from [1,4,4,48,48])
//   e [32768,4] f32
//   out[n] = argmin_k fl( fl(x2+e2) - 2*fl(dot) ), first-min tie semantics.
//
// Round 9:
//  - Rounds 5-8: time invariant to occupancy (26/47/35%) and regalloc; scalar
//    rewrite gave only -5%. Static floor ~35us vs measured 78.6us. Derived
//    VALUBusy/Occupancy use gfx94x formulas (4-cyc wave64 issue) on a 2-cyc
//    CDNA4 chip -> likely ~2x inflated; real issue occupancy ~38% => the
//    kernel is STALL-bound (dep-chain + L2 latency), not issue-bound.
//  - Lever 1: prefetch depth 1 -> 3. EPT=1 (4-reg chunks), 4 rotating
//    buffers (16 VGPR, same total as old 2x8), 64 chunks unrolled x4. Each
//    load gets ~3 compute-chunks (~720 cyc) of latency cover vs ~480.
//  - Lever 2: 4-wide ILP in the min-update: compute d[0..3] for 4 rows, then
//    4 compare-selects -> breaks the serial fma->cmp->cndmask chain, lets
//    the scheduler overlap independent chains.
//  - Arithmetic op-for-op identical to round 8 (bitwise-same distances).

#define ROWS   12
#define BLOCK  512
#define WAVES  (BLOCK / 64)
#define NK     32768
#define CHUNKS (NK / BLOCK)   // 64 chunks of 512 entries

__device__ __forceinline__ float rlf(float v) {
    return __builtin_bit_cast(float,
        __builtin_amdgcn_readfirstlane(__builtin_bit_cast(int, v)));
}

__global__ __launch_bounds__(BLOCK)
__attribute__((amdgpu_waves_per_eu(3, 4)))
void vq_argmin_kernel(const float* __restrict__ hs,
                      const float4* __restrict__ cb,
                      int* __restrict__ out)
{
    __shared__ float sRD[WAVES * ROWS];
    __shared__ int   sRI[WAVES * ROWS];

    const int tid = threadIdx.x;
    const int rowbase = blockIdx.x * ROWS;

    // Block-uniform x components -> readfirstlane into SGPRs.
    float sx0[ROWS], sx1[ROWS], sx2[ROWS], sx3[ROWS], sq[ROWS];
    float best[ROWS];
    int   bidx[ROWS];   // stores chunk index c; k = c*BLOCK + tid

    #pragma unroll
    for (int r = 0; r < ROWS; ++r) {
        int n = rowbase + r;
        int t = n / 2304;                 // 2304 = 48*48
        int rem = n - t * 2304;
        const float* ptr = hs + t * 9216 + rem;   // + c*2304 per channel
        float a0 = ptr[0], a1 = ptr[2304], a2 = ptr[4608], a3 = ptr[6912];
        float q = __fadd_rn(__fadd_rn(__fadd_rn(__fmul_rn(a0, a0),
                                                __fmul_rn(a1, a1)),
                                      __fmul_rn(a2, a2)),
                            __fmul_rn(a3, a3));
        sx0[r] = rlf(a0); sx1[r] = rlf(a1);
        sx2[r] = rlf(a2); sx3[r] = rlf(a3);
        sq[r]  = rlf(q);
        best[r] = FLT_MAX; bidx[r] = 0;
    }

    float4 b0, b1, b2, b3;

    auto ld = [&](float4& b, int c) {
        b = cb[(c & (CHUNKS - 1)) * BLOCK + tid];   // &63 wrap keeps tail legal
    };
    auto comp = [&](const float4& e, int c) {
        float e2 = __fadd_rn(__fadd_rn(__fadd_rn(__fmul_rn(e.x, e.x),
                                                 __fmul_rn(e.y, e.y)),
                                       __fmul_rn(e.z, e.z)),
                             __fmul_rn(e.w, e.w));
        #pragma unroll
        for (int g = 0; g < ROWS / 4; ++g) {
            float d[4];
            #pragma unroll
            for (int u = 0; u < 4; ++u) {
                int r = 4 * g + u;
                float dot = __fmul_rn(sx0[r], e.x);
                dot = __fmaf_rn(sx1[r], e.y, dot);
                dot = __fmaf_rn(sx2[r], e.z, dot);
                dot = __fmaf_rn(sx3[r], e.w, dot);
                float t1 = __fadd_rn(sq[r], e2);
                d[u] = __fmaf_rn(dot, -2.0f, t1);
            }
            #pragma unroll
            for (int u = 0; u < 4; ++u) {
                int r = 4 * g + u;
                if (d[u] < best[r]) { best[r] = d[u]; bidx[r] = c; }
            }
        }
    };

    // ---- 4-buffer rotating K loop, prefetch distance 3
    ld(b0, 0); ld(b1, 1); ld(b2, 2);
    for (int c = 0; c < CHUNKS; c += 4) {
        ld(b3, c + 3); comp(b0, c);
        ld(b0, c + 4); comp(b1, c + 1);
        ld(b1, c + 5); comp(b2, c + 2);
        ld(b2, c + 6); comp(b3, c + 3);
    }

    // ---- expand chunk index -> full codebook index, then reduce
    int kk[ROWS];
    #pragma unroll
    for (int r = 0; r < ROWS; ++r) kk[r] = bidx[r] * BLOCK + tid;

    // wave-level lexicographic (dist, idx) butterfly reduction
    #pragma unroll
    for (int r = 0; r < ROWS; ++r) {
        float d = best[r]; int i = kk[r];
        #pragma unroll
        for (int off = 32; off >= 1; off >>= 1) {
            float d2 = __shfl_xor(d, off, 64);
            int   i2 = __shfl_xor(i, off, 64);
            if (d2 < d || (d2 == d && i2 < i)) { d = d2; i = i2; }
        }
        best[r] = d; kk[r] = i;
    }

    int wave = tid >> 6;
    if ((tid & 63) == 0) {
        #pragma unroll
        for (int r = 0; r < ROWS; ++r) {
            sRD[wave * ROWS + r] = best[r];
            sRI[wave * ROWS + r] = kk[r];
        }
    }
    __syncthreads();

    if (tid < ROWS) {
        float d = sRD[tid]; int i = sRI[tid];
        #pragma unroll
        for (int w = 1; w < WAVES; ++w) {
            float d2 = sRD[w * ROWS + tid];
            int   i2 = sRI[w * ROWS + tid];
            if (d2 < d || (d2 == d && i2 < i)) { d = d2; i = i2; }
        }
        out[rowbase + tid] = i;
    }
}

extern "C" void kernel_launch(void* const* d_in, const int* in_sizes, int n_in,
                              void* d_out, int out_size, void* d_ws, size_t ws_size,
                              hipStream_t stream)
{
    const float*  hs = (const float*)d_in[0];    // [1,4,4,48,48]
    const float4* cb = (const float4*)d_in[1];   // [32768,4]
    int* out = (int*)d_out;                      // [9216] int32

    const int nrows = 9216;
    dim3 grid(nrows / ROWS), block(BLOCK);
    vq_argmin_kernel<<<grid, block, 0, stream>>>(hs, cb, out);
}